// Round 13
// baseline (510.051 us; speedup 1.0000x reference)
//
#include <hip/hip_runtime.h>
#include <hip/hip_bf16.h>

#define BATCH 2
#define LSEQ 4096
#define M (BATCH*LSEQ)   // 8192 rows
#define D 128
#define P 64
#define NL 2
#define VOCAB 32000
#define DFF 512

typedef __attribute__((ext_vector_type(8))) short bf16x8_t;
typedef __attribute__((ext_vector_type(4))) float f32x4_t;

__device__ inline unsigned short f2bf(float f) {
    unsigned int u = __float_as_uint(f);
    unsigned int r = (u + 0x7fffu + ((u >> 16) & 1u)) >> 16;
    return (unsigned short)r;
}
__device__ inline float bf2f(unsigned short u) {
    return __uint_as_float(((unsigned int)u) << 16);
}

// Fused prologue: all 5 prep kernels as disjoint block ranges of ONE dispatch
// (R10: -10us). Section math byte-identical to the unfused kernels.
//  [0,1024)      embed: h/hb
//  [1024,5024)   Wout -> wt transpose
//  [5024,5280)   bqkv (WqpT/WkpT/WvT)
//  [5280,5792)   W1T
//  [5792,6304)   W2T
__global__ __launch_bounds__(256) void k_prep_all(const int* __restrict__ tokens,
                                                  const float* __restrict__ embed,
                                                  const float* __restrict__ pos,
                                                  float* __restrict__ h,
                                                  unsigned short* __restrict__ hb,
                                                  const float* __restrict__ Wout,
                                                  unsigned short* __restrict__ WT,
                                                  const float* __restrict__ Wq,
                                                  const float* __restrict__ Wk,
                                                  const float* __restrict__ Wv,
                                                  const float* __restrict__ proj,
                                                  unsigned short* __restrict__ bqkv,
                                                  const float* __restrict__ W1,
                                                  unsigned short* __restrict__ W1T,
                                                  const float* __restrict__ W2,
                                                  unsigned short* __restrict__ W2T) {
    __shared__ float tile[32][33];
    int b = blockIdx.x;
    int tid = threadIdx.x;
    if (b < 1024) {
        // ---- embed ----
        int gid = b * 256 + tid;               // over M*32 float4s
        int row = gid >> 5;
        int d4  = gid & 31;
        int l = row & (LSEQ - 1);
        int tok = tokens[row];
        float4 a = ((const float4*)(embed + (size_t)tok * D))[d4];
        float4 p4 = ((const float4*)(pos + (size_t)l * D))[d4];
        a.x += p4.x; a.y += p4.y; a.z += p4.z; a.w += p4.w;
        ((float4*)(h + (size_t)row * D))[d4] = a;
        ushort4 u; u.x = f2bf(a.x); u.y = f2bf(a.y); u.z = f2bf(a.z); u.w = f2bf(a.w);
        ((ushort4*)(hb + (size_t)row * D))[d4] = u;
    } else if (b < 5024) {
        // ---- Wout transpose ----
        int bb = b - 1024;
        int v0 = (bb % 1000) * 32, d0 = (bb / 1000) * 32;
        int tx = tid & 31, ty = tid >> 5;
        for (int i = ty; i < 32; i += 8)
            tile[i][tx] = Wout[(size_t)(d0 + i) * VOCAB + v0 + tx];
        __syncthreads();
        for (int i = ty; i < 32; i += 8)
            WT[(size_t)(v0 + i) * D + d0 + tx] = f2bf(tile[tx][i]);
    } else if (b < 5280) {
        // ---- bqkv ----
        int idx = (b - 5024) * 256 + tid;      // 2*256*128
        int d = idx & 127;
        int r = (idx >> 7) & 255;
        int l = idx >> 15;
        const float* WqL = Wq + (size_t)l * D * D;
        const float* WkL = Wk + (size_t)l * D * D;
        const float* WvL = Wv + (size_t)l * D * D;
        const float* pjL = proj + (size_t)l * D * P;
        float val;
        if (r < 128) {
            const float* W = (r < 64) ? WqL : WkL;
            int p = r & 63;
            float s = 0.f;
            for (int e = 0; e < D; e++) s = fmaf(W[d * D + e], pjL[e * P + p], s);
            val = s;
        } else {
            val = WvL[d * D + (r - 128)];
        }
        bqkv[((size_t)l * 256 + r) * D + d] = f2bf(val);
    } else if (b < 5792) {
        // ---- W1T ----
        int idx = (b - 5280) * 256 + tid;      // 2*512*128
        int d = idx & 127;
        int n = (idx >> 7) & 511;
        int l = idx >> 16;
        W1T[((size_t)l * DFF + n) * D + d] = f2bf(W1[((size_t)l * D + d) * DFF + n]);
    } else {
        // ---- W2T ----
        int idx = (b - 5792) * 256 + tid;      // 2*128*512
        int f = idx & 511;
        int n = (idx >> 9) & 127;
        int l = idx >> 16;
        W2T[((size_t)l * D + n) * DFF + f] = f2bf(W2[((size_t)l * DFF + f) * D + n]);
    }
}

// Fused projections: C[M x 256] = hb @ BqkvT^T ; cols 0-63 -> qp=elu(x)+1 (f32),
// 64-127 -> kp (f32), 128-255 -> vb (bf16). Tile 32 rows x 256 cols, 4 waves.
// Block 0 additionally zeroes kv for this layer (consumed by kvpart's atomics;
// safe: attnffn of the previous layer finished at the kernel boundary).
// R11 LESSON: __threadfence() inside a kernel = device-scope release on
// non-coherent per-XCD L2s = L2 writeback per block (-166us!). Cross-block
// dataflow must use kernel boundaries or atomics (G12/m20: cheap), never fences.
__global__ __launch_bounds__(256) void k_qkvp(const unsigned short* __restrict__ hb,
                                              const unsigned short* __restrict__ Bt,
                                              float* __restrict__ qp, float* __restrict__ kp,
                                              unsigned short* __restrict__ vb,
                                              float* __restrict__ kv) {
    if (blockIdx.x == 0) {   // zero kv (BATCH*P*D f32 = 64KB) for atomic accumulation
        float4 z = make_float4(0.f, 0.f, 0.f, 0.f);
        float4* kv4 = (float4*)kv;
        for (int i = threadIdx.x; i < BATCH * P * D / 4; i += 256) kv4[i] = z;
    }
    int r0 = blockIdx.x * 32;
    int wid = threadIdx.x >> 6;
    int lane = threadIdx.x & 63;
    int c0 = wid * 64;
    int lr = lane & 15;
    int lk = (lane >> 4) * 8;
    const short* Ap = (const short*)hb;
    const short* Bp = (const short*)Bt;
    f32x4_t acc[2][4] = {};
    #pragma unroll
    for (int kc = 0; kc < 4; kc++) {
        bf16x8_t af[2], bfr[4];
        #pragma unroll
        for (int mi = 0; mi < 2; mi++)
            af[mi] = *(const bf16x8_t*)(Ap + (size_t)(r0 + mi * 16 + lr) * D + kc * 32 + lk);
        #pragma unroll
        for (int ni = 0; ni < 4; ni++)
            bfr[ni] = *(const bf16x8_t*)(Bp + (size_t)(c0 + ni * 16 + lr) * D + kc * 32 + lk);
        #pragma unroll
        for (int mi = 0; mi < 2; mi++)
            #pragma unroll
            for (int ni = 0; ni < 4; ni++)
                acc[mi][ni] = __builtin_amdgcn_mfma_f32_16x16x32_bf16(af[mi], bfr[ni], acc[mi][ni], 0, 0, 0);
    }
    int orow = (lane >> 4) * 4;
    if (wid < 2) {  // qp / kp with elu(x)+1, f32 out
        float* out = (wid == 0) ? qp : kp;
        #pragma unroll
        for (int mi = 0; mi < 2; mi++)
            #pragma unroll
            for (int ni = 0; ni < 4; ni++)
                #pragma unroll
                for (int j = 0; j < 4; j++) {
                    float x = acc[mi][ni][j];
                    float e = x > 0.f ? x + 1.f : __expf(x);
                    out[(size_t)(r0 + mi * 16 + orow + j) * P + ni * 16 + lr] = e;
                }
    } else {        // vb bf16 out, cols (wid-2)*64 + ...
        int cb = (wid - 2) * 64;
        #pragma unroll
        for (int mi = 0; mi < 2; mi++)
            #pragma unroll
            for (int ni = 0; ni < 4; ni++)
                #pragma unroll
                for (int j = 0; j < 4; j++)
                    vb[(size_t)(r0 + mi * 16 + orow + j) * D + cb + ni * 16 + lr] = f2bf(acc[mi][ni][j]);
    }
}

// partial kv, accumulated straight into kv via device-scope atomicAdd
// (replaces part buffer + kvred kernel; no fences — atomics execute at the
// device-coherent point without L2 flush). 16-way per-address contention,
// ~1MB total RMW traffic. Summation order of the 16 chunk partials becomes
// nondeterministic: f32 reshuffle of 16 terms, ~ulp-scale, benign.
__global__ void k_kvpart(const float* __restrict__ kp, const unsigned short* __restrict__ vb,
                         float* __restrict__ kv) {
    int p = blockIdx.x, ch = blockIdx.y, b = blockIdx.z, d = threadIdx.x;
    const float* kpb = kp + (size_t)b * LSEQ * P + p;
    const unsigned short* vbp = vb + (size_t)b * LSEQ * D + d;
    int l0 = ch * 256;
    float a0 = 0.f, a1 = 0.f, a2 = 0.f, a3 = 0.f;
    for (int l = l0; l < l0 + 256; l += 4) {
        a0 = fmaf(kpb[(size_t)l * P],       bf2f(vbp[(size_t)l * D]),       a0);
        a1 = fmaf(kpb[(size_t)(l + 1) * P], bf2f(vbp[(size_t)(l + 1) * D]), a1);
        a2 = fmaf(kpb[(size_t)(l + 2) * P], bf2f(vbp[(size_t)(l + 2) * D]), a2);
        a3 = fmaf(kpb[(size_t)(l + 3) * P], bf2f(vbp[(size_t)(l + 3) * D]), a3);
    }
    atomicAdd(&kv[((size_t)b * P + p) * D + d], (a0 + a1) + (a2 + a3));
}

// Fused attn + LN + FFN per 16-row tile:
//   attn = (qp @ kv) / (sum_p qp + eps)
//   a    = layernorm(attn)*g + b          -> bf16 tile in LDS (stride 136)
//   h   += gelu(a @ W1T^T + b1) @ W2T^T + b2; hb = bf16(h)
// attn/LN thread layout: row = tid>>4 (16 rows), 8 d-elems per thread;
// LN reduction = pure 16-lane shfl_xor tree (no LDS, no barriers).
#define TSTRIDE 520
#define ABSTRIDE 136
__global__ __launch_bounds__(256) void k_attnffn(const float* __restrict__ qp,
                                                 const float* __restrict__ kv,
                                                 const float* __restrict__ lng,
                                                 const float* __restrict__ lnb,
                                                 const unsigned short* __restrict__ W1T,
                                                 const float* __restrict__ b1,
                                                 const unsigned short* __restrict__ W2T,
                                                 const float* __restrict__ b2,
                                                 float* __restrict__ h,
                                                 unsigned short* __restrict__ hb) {
    __shared__ unsigned short abt[16 * ABSTRIDE];  // 4.4 KB
    __shared__ unsigned short tl[16 * TSTRIDE];    // 16.6 KB
    int r0 = blockIdx.x * 16;
    int b = r0 >> 12;
    int tid = threadIdx.x;
    // ---- attn + LN: row = tid>>4, d0 = (tid&15)*8 ----
    {
        int row16 = tid >> 4;
        int dq = tid & 15;
        int d0 = dq * 8;
        const float* qpr = qp + (size_t)(r0 + row16) * P;
        const float4* kv4 = (const float4*)(kv + (size_t)b * P * D);
        float num[8] = {};
        float zs = 0.f;
        #pragma unroll 8
        for (int p = 0; p < P; p++) {
            float qv = qpr[p];
            zs += qv;
            float4 v0 = kv4[p * 32 + dq * 2];
            float4 v1 = kv4[p * 32 + dq * 2 + 1];
            num[0] = fmaf(qv, v0.x, num[0]);
            num[1] = fmaf(qv, v0.y, num[1]);
            num[2] = fmaf(qv, v0.z, num[2]);
            num[3] = fmaf(qv, v0.w, num[3]);
            num[4] = fmaf(qv, v1.x, num[4]);
            num[5] = fmaf(qv, v1.y, num[5]);
            num[6] = fmaf(qv, v1.z, num[6]);
            num[7] = fmaf(qv, v1.w, num[7]);
        }
        float rz = 1.f / (zs + 1e-8f);
        float attn[8];
        float s = 0.f;
        #pragma unroll
        for (int j = 0; j < 8; j++) { attn[j] = num[j] * rz; s += attn[j]; }
        #pragma unroll
        for (int m = 1; m < 16; m <<= 1) s += __shfl_xor(s, m);
        float mu = s * (1.f / 128.f);
        float dv[8];
        float s2 = 0.f;
        #pragma unroll
        for (int j = 0; j < 8; j++) { dv[j] = attn[j] - mu; s2 = fmaf(dv[j], dv[j], s2); }
        #pragma unroll
        for (int m = 1; m < 16; m <<= 1) s2 += __shfl_xor(s2, m);
        float rs = rsqrtf(s2 * (1.f / 128.f) + 1e-5f);
        #pragma unroll
        for (int j = 0; j < 8; j++) {
            float o = dv[j] * rs * lng[d0 + j] + lnb[d0 + j];
            abt[row16 * ABSTRIDE + d0 + j] = f2bf(o);
        }
    }
    __syncthreads();
    // ---- FFN phase 1: 16 x 128 cols per wave, K=128, A from LDS ----
    int wid = tid >> 6;
    int lane = tid & 63;
    int lr = lane & 15;
    int lk = (lane >> 4) * 8;
    int orow = (lane >> 4) * 4;
    const short* B1 = (const short*)W1T;
    int c0 = wid * 128;
    f32x4_t acc1[8] = {};
    #pragma unroll
    for (int kc = 0; kc < 4; kc++) {
        bf16x8_t af = *(const bf16x8_t*)(abt + lr * ABSTRIDE + kc * 32 + lk);
        bf16x8_t bfr[8];
        #pragma unroll
        for (int ni = 0; ni < 8; ni++)
            bfr[ni] = *(const bf16x8_t*)(B1 + (size_t)(c0 + ni * 16 + lr) * D + kc * 32 + lk);
        #pragma unroll
        for (int ni = 0; ni < 8; ni++)
            acc1[ni] = __builtin_amdgcn_mfma_f32_16x16x32_bf16(af, bfr[ni], acc1[ni], 0, 0, 0);
    }
    #pragma unroll
    for (int ni = 0; ni < 8; ni++) {
        int col = c0 + ni * 16 + lr;
        float bias = b1[col];
        #pragma unroll
        for (int j = 0; j < 4; j++) {
            float x = acc1[ni][j] + bias;
            float g = 0.5f * x * (1.f + erff(x * 0.70710678f));
            tl[(orow + j) * TSTRIDE + col] = f2bf(g);
        }
    }
    __syncthreads();
    // ---- FFN phase 2: 16 x 32 cols per wave, K=512 from LDS ----
    int c2 = wid * 32;
    const short* B2 = (const short*)W2T;
    f32x4_t acc2[2] = {};
    #pragma unroll 4
    for (int kc = 0; kc < 16; kc++) {
        bf16x8_t af, bfr[2];
        af = *(const bf16x8_t*)(tl + (size_t)lr * TSTRIDE + kc * 32 + lk);
        #pragma unroll
        for (int ni = 0; ni < 2; ni++)
            bfr[ni] = *(const bf16x8_t*)(B2 + (size_t)(c2 + ni * 16 + lr) * DFF + kc * 32 + lk);
        #pragma unroll
        for (int ni = 0; ni < 2; ni++)
            acc2[ni] = __builtin_amdgcn_mfma_f32_16x16x32_bf16(af, bfr[ni], acc2[ni], 0, 0, 0);
    }
    #pragma unroll
    for (int ni = 0; ni < 2; ni++) {
        int col = c2 + ni * 16 + lr;
        float bias = b2[col];
        #pragma unroll
        for (int j = 0; j < 4; j++) {
            size_t idx = (size_t)(r0 + orow + j) * D + col;
            float hn = h[idx] + acc2[ni][j] + bias;
            h[idx] = hn;
            hb[idx] = f2bf(hn);
        }
    }
}

// logits = hb(bf16 [M,128]) @ wt^T(bf16 [VOCAB,128]) -> f32 [M,VOCAB]
// R9 structure: B tile in LDS w/ XOR swizzle, 4 row-bands (bg=16, 4000 blocks),
// bx-fastest grid, mfma(af,bfr), scalar NONTEMPORAL stores.
// ONE change vs R12: __launch_bounds__(256, 4) — request 4 blocks/CU
// (caps VGPR at 128/thread; acc 64 + af/bfr 32 + addr ~25 should fit).
// Theory: allocator was landing just above 128 -> 3 waves/SIMD; the 4th
// block/CU adds waves to overlap one block's MFMA burst with another's
// store drain. LDS 4 x 32KB = 128KB <= 160KB OK.
__global__ __launch_bounds__(256, 4) void k_gemm_out(const unsigned short* __restrict__ A,
                                                     const unsigned short* __restrict__ Bt,
                                                     float* __restrict__ C) {
    __shared__ unsigned short bl[128 * 128];   // 32 KB B tile
    int bx = blockIdx.x;             // VOCAB/128 = 250 (fastest)
    int bg = blockIdx.y;             // 16 band groups of 4 bands
    int tid = threadIdx.x;
    // stage B tile (contiguous 32 KB at Bt + bx*128*D) with row-XOR swizzle
    {
        const bf16x8_t* src = (const bf16x8_t*)((const short*)Bt + (size_t)bx * 128 * D);
        int row = tid >> 1;
        int base = (tid & 1) * 128;              // byte base within 256B row
        char* dst = (char*)bl + row * 256;
        #pragma unroll
        for (int i = 0; i < 8; i++) {
            int boff = base + i * 16;
            *(bf16x8_t*)(dst + (boff ^ ((row & 7) << 4))) = src[tid * 8 + i];
        }
    }
    __syncthreads();
    int wid = tid >> 6;
    int lane = tid & 63;
    int wr = wid >> 1, wc = wid & 1;
    int lr = lane & 15;
    int hi = lane >> 4;
    int lk = hi * 8;
    int col0 = bx * 128 + wc * 64;
    const short* Ap = (const short*)A;
    #pragma unroll 1
    for (int w = 0; w < 4; w++) {
        int row0 = (bg * 4 + w) * 128 + wr * 64;
        f32x4_t acc[4][4] = {};
        #pragma unroll
        for (int kc = 0; kc < 4; kc++) {
            bf16x8_t af[4], bfr[4];
            #pragma unroll
            for (int mi = 0; mi < 4; mi++)
                af[mi] = *(const bf16x8_t*)(Ap + (size_t)(row0 + mi * 16 + lr) * D + kc * 32 + lk);
            #pragma unroll
            for (int ni = 0; ni < 4; ni++) {
                int brow = wc * 64 + ni * 16 + lr;
                int boff = kc * 64 + hi * 16;
                bfr[ni] = *(const bf16x8_t*)((const char*)bl + brow * 256 + (boff ^ ((brow & 7) << 4)));
            }
            #pragma unroll
            for (int mi = 0; mi < 4; mi++)
                #pragma unroll
                for (int ni = 0; ni < 4; ni++)
                    acc[mi][ni] = __builtin_amdgcn_mfma_f32_16x16x32_bf16(af[mi], bfr[ni], acc[mi][ni], 0, 0, 0);
        }
        int orow = hi * 4;
        #pragma unroll
        for (int mi = 0; mi < 4; mi++)
            #pragma unroll
            for (int ni = 0; ni < 4; ni++)
                #pragma unroll
                for (int j = 0; j < 4; j++)
                    __builtin_nontemporal_store(acc[mi][ni][j],
                        &C[(size_t)(row0 + mi * 16 + orow + j) * VOCAB + col0 + ni * 16 + lr]);
    }
}

extern "C" void kernel_launch(void* const* d_in, const int* in_sizes, int n_in,
                              void* d_out, int out_size, void* d_ws, size_t ws_size,
                              hipStream_t stream) {
    const int*   tokens = (const int*)d_in[0];
    const float* embed  = (const float*)d_in[1];
    const float* pos    = (const float*)d_in[2];
    const float* Wq     = (const float*)d_in[3];
    const float* Wk     = (const float*)d_in[4];
    const float* Wv     = (const float*)d_in[5];
    const float* proj   = (const float*)d_in[6];
    const float* lng    = (const float*)d_in[7];
    const float* lnb    = (const float*)d_in[8];
    const float* W1     = (const float*)d_in[9];
    const float* b1     = (const float*)d_in[10];
    const float* W2     = (const float*)d_in[11];
    const float* b2     = (const float*)d_in[12];
    const float* Wout   = (const float*)d_in[13];
    float* out = (float*)d_out;
    char* ws = (char*)d_ws;

    // ws layout (MB offsets)
    float*          h    = (float*)(ws);                               // [0,4)
    unsigned short* hb   = (unsigned short*)(ws + ((size_t)4  << 20)); // [4,6)
    float*          qp   = (float*)(ws + ((size_t)6  << 20));          // [6,8)
    float*          kp   = (float*)(ws + ((size_t)8  << 20));          // [8,10)
    unsigned short* vb   = (unsigned short*)(ws + ((size_t)10 << 20)); // [10,12)
    float*          kv   = (float*)(ws + ((size_t)13 << 20));          // 64KB
    unsigned short* wt   = (unsigned short*)(ws + ((size_t)24 << 20)); // [24,32)
    unsigned short* bqkv = (unsigned short*)(ws + ((size_t)32 << 20)); // 128KB
    unsigned short* w1t  = (unsigned short*)(ws + ((size_t)33 << 20)); // 256KB
    unsigned short* w2t  = (unsigned short*)(ws + ((size_t)34 << 20)); // 256KB

    k_prep_all<<<dim3(6304), dim3(256), 0, stream>>>(tokens, embed, pos, h, hb,
                                                     Wout, wt, Wq, Wk, Wv, proj, bqkv,
                                                     W1, w1t, W2, w2t);

    for (int i = 0; i < NL; i++) {
        k_qkvp<<<dim3(M / 32), dim3(256), 0, stream>>>(hb, bqkv + (size_t)i * 256 * D, qp, kp, vb, kv);
        k_kvpart<<<dim3(P, 16, BATCH), dim3(128), 0, stream>>>(kp, vb, kv);
        k_attnffn<<<dim3(M / 16), dim3(256), 0, stream>>>(qp, kv, lng + (size_t)i * D, lnb + (size_t)i * D,
                                                          w1t + (size_t)i * DFF * D, b1 + (size_t)i * DFF,
                                                          w2t + (size_t)i * D * DFF, b2 + (size_t)i * D, h, hb);
    }

    k_gemm_out<<<dim3(VOCAB / 128, M / 128 / 4), dim3(256), 0, stream>>>(hb, wt, out);
}

// Round 14
// 365.682 us; speedup vs baseline: 1.3948x; 1.3948x over previous
//
#include <hip/hip_runtime.h>
#include <hip/hip_bf16.h>

#define BATCH 2
#define LSEQ 4096
#define M (BATCH*LSEQ)   // 8192 rows
#define D 128
#define P 64
#define NL 2
#define VOCAB 32000
#define DFF 512

typedef __attribute__((ext_vector_type(8))) short bf16x8_t;
typedef __attribute__((ext_vector_type(4))) float f32x4_t;

__device__ inline unsigned short f2bf(float f) {
    unsigned int u = __float_as_uint(f);
    unsigned int r = (u + 0x7fffu + ((u >> 16) & 1u)) >> 16;
    return (unsigned short)r;
}
__device__ inline float bf2f(unsigned short u) {
    return __uint_as_float(((unsigned int)u) << 16);
}

// Fused prologue: all 5 prep kernels as disjoint block ranges of ONE dispatch
// (R10: -10us). Section math byte-identical to the unfused kernels.
//  [0,1024)      embed: h/hb
//  [1024,5024)   Wout -> wt transpose
//  [5024,5280)   bqkv (WqpT/WkpT/WvT)
//  [5280,5792)   W1T
//  [5792,6304)   W2T
__global__ __launch_bounds__(256) void k_prep_all(const int* __restrict__ tokens,
                                                  const float* __restrict__ embed,
                                                  const float* __restrict__ pos,
                                                  float* __restrict__ h,
                                                  unsigned short* __restrict__ hb,
                                                  const float* __restrict__ Wout,
                                                  unsigned short* __restrict__ WT,
                                                  const float* __restrict__ Wq,
                                                  const float* __restrict__ Wk,
                                                  const float* __restrict__ Wv,
                                                  const float* __restrict__ proj,
                                                  unsigned short* __restrict__ bqkv,
                                                  const float* __restrict__ W1,
                                                  unsigned short* __restrict__ W1T,
                                                  const float* __restrict__ W2,
                                                  unsigned short* __restrict__ W2T) {
    __shared__ float tile[32][33];
    int b = blockIdx.x;
    int tid = threadIdx.x;
    if (b < 1024) {
        // ---- embed ----
        int gid = b * 256 + tid;               // over M*32 float4s
        int row = gid >> 5;
        int d4  = gid & 31;
        int l = row & (LSEQ - 1);
        int tok = tokens[row];
        float4 a = ((const float4*)(embed + (size_t)tok * D))[d4];
        float4 p4 = ((const float4*)(pos + (size_t)l * D))[d4];
        a.x += p4.x; a.y += p4.y; a.z += p4.z; a.w += p4.w;
        ((float4*)(h + (size_t)row * D))[d4] = a;
        ushort4 u; u.x = f2bf(a.x); u.y = f2bf(a.y); u.z = f2bf(a.z); u.w = f2bf(a.w);
        ((ushort4*)(hb + (size_t)row * D))[d4] = u;
    } else if (b < 5024) {
        // ---- Wout transpose ----
        int bb = b - 1024;
        int v0 = (bb % 1000) * 32, d0 = (bb / 1000) * 32;
        int tx = tid & 31, ty = tid >> 5;
        for (int i = ty; i < 32; i += 8)
            tile[i][tx] = Wout[(size_t)(d0 + i) * VOCAB + v0 + tx];
        __syncthreads();
        for (int i = ty; i < 32; i += 8)
            WT[(size_t)(v0 + i) * D + d0 + tx] = f2bf(tile[tx][i]);
    } else if (b < 5280) {
        // ---- bqkv ----
        int idx = (b - 5024) * 256 + tid;      // 2*256*128
        int d = idx & 127;
        int r = (idx >> 7) & 255;
        int l = idx >> 15;
        const float* WqL = Wq + (size_t)l * D * D;
        const float* WkL = Wk + (size_t)l * D * D;
        const float* WvL = Wv + (size_t)l * D * D;
        const float* pjL = proj + (size_t)l * D * P;
        float val;
        if (r < 128) {
            const float* W = (r < 64) ? WqL : WkL;
            int p = r & 63;
            float s = 0.f;
            for (int e = 0; e < D; e++) s = fmaf(W[d * D + e], pjL[e * P + p], s);
            val = s;
        } else {
            val = WvL[d * D + (r - 128)];
        }
        bqkv[((size_t)l * 256 + r) * D + d] = f2bf(val);
    } else if (b < 5792) {
        // ---- W1T ----
        int idx = (b - 5280) * 256 + tid;      // 2*512*128
        int d = idx & 127;
        int n = (idx >> 7) & 511;
        int l = idx >> 16;
        W1T[((size_t)l * DFF + n) * D + d] = f2bf(W1[((size_t)l * D + d) * DFF + n]);
    } else {
        // ---- W2T ----
        int idx = (b - 5792) * 256 + tid;      // 2*128*512
        int f = idx & 511;
        int n = (idx >> 9) & 127;
        int l = idx >> 16;
        W2T[((size_t)l * D + n) * DFF + f] = f2bf(W2[((size_t)l * DFF + f) * D + n]);
    }
}

// Fused projections: C[M x 256] = hb @ BqkvT^T ; cols 0-63 -> qp=elu(x)+1 (f32),
// 64-127 -> kp (f32), 128-255 -> vb (bf16). Tile 32 rows x 256 cols, 4 waves.
// Block 0 additionally zeroes kv for this layer (consumed by kvpart's atomics;
// safe: attnffn of the previous layer finished at the kernel boundary).
// R11 LESSON: __threadfence() inside a kernel = device-scope release on
// non-coherent per-XCD L2s = L2 writeback per block (-166us!). Cross-block
// dataflow must use kernel boundaries or atomics (G12/m20: cheap), never fences.
__global__ __launch_bounds__(256) void k_qkvp(const unsigned short* __restrict__ hb,
                                              const unsigned short* __restrict__ Bt,
                                              float* __restrict__ qp, float* __restrict__ kp,
                                              unsigned short* __restrict__ vb,
                                              float* __restrict__ kv) {
    if (blockIdx.x == 0) {   // zero kv (BATCH*P*D f32 = 64KB) for atomic accumulation
        float4 z = make_float4(0.f, 0.f, 0.f, 0.f);
        float4* kv4 = (float4*)kv;
        for (int i = threadIdx.x; i < BATCH * P * D / 4; i += 256) kv4[i] = z;
    }
    int r0 = blockIdx.x * 32;
    int wid = threadIdx.x >> 6;
    int lane = threadIdx.x & 63;
    int c0 = wid * 64;
    int lr = lane & 15;
    int lk = (lane >> 4) * 8;
    const short* Ap = (const short*)hb;
    const short* Bp = (const short*)Bt;
    f32x4_t acc[2][4] = {};
    #pragma unroll
    for (int kc = 0; kc < 4; kc++) {
        bf16x8_t af[2], bfr[4];
        #pragma unroll
        for (int mi = 0; mi < 2; mi++)
            af[mi] = *(const bf16x8_t*)(Ap + (size_t)(r0 + mi * 16 + lr) * D + kc * 32 + lk);
        #pragma unroll
        for (int ni = 0; ni < 4; ni++)
            bfr[ni] = *(const bf16x8_t*)(Bp + (size_t)(c0 + ni * 16 + lr) * D + kc * 32 + lk);
        #pragma unroll
        for (int mi = 0; mi < 2; mi++)
            #pragma unroll
            for (int ni = 0; ni < 4; ni++)
                acc[mi][ni] = __builtin_amdgcn_mfma_f32_16x16x32_bf16(af[mi], bfr[ni], acc[mi][ni], 0, 0, 0);
    }
    int orow = (lane >> 4) * 4;
    if (wid < 2) {  // qp / kp with elu(x)+1, f32 out
        float* out = (wid == 0) ? qp : kp;
        #pragma unroll
        for (int mi = 0; mi < 2; mi++)
            #pragma unroll
            for (int ni = 0; ni < 4; ni++)
                #pragma unroll
                for (int j = 0; j < 4; j++) {
                    float x = acc[mi][ni][j];
                    float e = x > 0.f ? x + 1.f : __expf(x);
                    out[(size_t)(r0 + mi * 16 + orow + j) * P + ni * 16 + lr] = e;
                }
    } else {        // vb bf16 out, cols (wid-2)*64 + ...
        int cb = (wid - 2) * 64;
        #pragma unroll
        for (int mi = 0; mi < 2; mi++)
            #pragma unroll
            for (int ni = 0; ni < 4; ni++)
                #pragma unroll
                for (int j = 0; j < 4; j++)
                    vb[(size_t)(r0 + mi * 16 + orow + j) * D + cb + ni * 16 + lr] = f2bf(acc[mi][ni][j]);
    }
}

// partial kv, accumulated straight into kv via device-scope atomicAdd
// (replaces part buffer + kvred kernel; no fences — atomics execute at the
// device-coherent point without L2 flush). 16-way per-address contention,
// ~1MB total RMW traffic. Summation order of the 16 chunk partials becomes
// nondeterministic: f32 reshuffle of 16 terms, ~ulp-scale, benign.
__global__ void k_kvpart(const float* __restrict__ kp, const unsigned short* __restrict__ vb,
                         float* __restrict__ kv) {
    int p = blockIdx.x, ch = blockIdx.y, b = blockIdx.z, d = threadIdx.x;
    const float* kpb = kp + (size_t)b * LSEQ * P + p;
    const unsigned short* vbp = vb + (size_t)b * LSEQ * D + d;
    int l0 = ch * 256;
    float a0 = 0.f, a1 = 0.f, a2 = 0.f, a3 = 0.f;
    for (int l = l0; l < l0 + 256; l += 4) {
        a0 = fmaf(kpb[(size_t)l * P],       bf2f(vbp[(size_t)l * D]),       a0);
        a1 = fmaf(kpb[(size_t)(l + 1) * P], bf2f(vbp[(size_t)(l + 1) * D]), a1);
        a2 = fmaf(kpb[(size_t)(l + 2) * P], bf2f(vbp[(size_t)(l + 2) * D]), a2);
        a3 = fmaf(kpb[(size_t)(l + 3) * P], bf2f(vbp[(size_t)(l + 3) * D]), a3);
    }
    atomicAdd(&kv[((size_t)b * P + p) * D + d], (a0 + a1) + (a2 + a3));
}

// Fused attn + LN + FFN per 16-row tile:
//   attn = (qp @ kv) / (sum_p qp + eps)
//   a    = layernorm(attn)*g + b          -> bf16 tile in LDS (stride 136)
//   h   += gelu(a @ W1T^T + b1) @ W2T^T + b2; hb = bf16(h)
// attn/LN thread layout: row = tid>>4 (16 rows), 8 d-elems per thread;
// LN reduction = pure 16-lane shfl_xor tree (no LDS, no barriers).
#define TSTRIDE 520
#define ABSTRIDE 136
__global__ __launch_bounds__(256) void k_attnffn(const float* __restrict__ qp,
                                                 const float* __restrict__ kv,
                                                 const float* __restrict__ lng,
                                                 const float* __restrict__ lnb,
                                                 const unsigned short* __restrict__ W1T,
                                                 const float* __restrict__ b1,
                                                 const unsigned short* __restrict__ W2T,
                                                 const float* __restrict__ b2,
                                                 float* __restrict__ h,
                                                 unsigned short* __restrict__ hb) {
    __shared__ unsigned short abt[16 * ABSTRIDE];  // 4.4 KB
    __shared__ unsigned short tl[16 * TSTRIDE];    // 16.6 KB
    int r0 = blockIdx.x * 16;
    int b = r0 >> 12;
    int tid = threadIdx.x;
    // ---- attn + LN: row = tid>>4, d0 = (tid&15)*8 ----
    {
        int row16 = tid >> 4;
        int dq = tid & 15;
        int d0 = dq * 8;
        const float* qpr = qp + (size_t)(r0 + row16) * P;
        const float4* kv4 = (const float4*)(kv + (size_t)b * P * D);
        float num[8] = {};
        float zs = 0.f;
        #pragma unroll 8
        for (int p = 0; p < P; p++) {
            float qv = qpr[p];
            zs += qv;
            float4 v0 = kv4[p * 32 + dq * 2];
            float4 v1 = kv4[p * 32 + dq * 2 + 1];
            num[0] = fmaf(qv, v0.x, num[0]);
            num[1] = fmaf(qv, v0.y, num[1]);
            num[2] = fmaf(qv, v0.z, num[2]);
            num[3] = fmaf(qv, v0.w, num[3]);
            num[4] = fmaf(qv, v1.x, num[4]);
            num[5] = fmaf(qv, v1.y, num[5]);
            num[6] = fmaf(qv, v1.z, num[6]);
            num[7] = fmaf(qv, v1.w, num[7]);
        }
        float rz = 1.f / (zs + 1e-8f);
        float attn[8];
        float s = 0.f;
        #pragma unroll
        for (int j = 0; j < 8; j++) { attn[j] = num[j] * rz; s += attn[j]; }
        #pragma unroll
        for (int m = 1; m < 16; m <<= 1) s += __shfl_xor(s, m);
        float mu = s * (1.f / 128.f);
        float dv[8];
        float s2 = 0.f;
        #pragma unroll
        for (int j = 0; j < 8; j++) { dv[j] = attn[j] - mu; s2 = fmaf(dv[j], dv[j], s2); }
        #pragma unroll
        for (int m = 1; m < 16; m <<= 1) s2 += __shfl_xor(s2, m);
        float rs = rsqrtf(s2 * (1.f / 128.f) + 1e-5f);
        #pragma unroll
        for (int j = 0; j < 8; j++) {
            float o = dv[j] * rs * lng[d0 + j] + lnb[d0 + j];
            abt[row16 * ABSTRIDE + d0 + j] = f2bf(o);
        }
    }
    __syncthreads();
    // ---- FFN phase 1: 16 x 128 cols per wave, K=128, A from LDS ----
    int wid = tid >> 6;
    int lane = tid & 63;
    int lr = lane & 15;
    int lk = (lane >> 4) * 8;
    int orow = (lane >> 4) * 4;
    const short* B1 = (const short*)W1T;
    int c0 = wid * 128;
    f32x4_t acc1[8] = {};
    #pragma unroll
    for (int kc = 0; kc < 4; kc++) {
        bf16x8_t af = *(const bf16x8_t*)(abt + lr * ABSTRIDE + kc * 32 + lk);
        bf16x8_t bfr[8];
        #pragma unroll
        for (int ni = 0; ni < 8; ni++)
            bfr[ni] = *(const bf16x8_t*)(B1 + (size_t)(c0 + ni * 16 + lr) * D + kc * 32 + lk);
        #pragma unroll
        for (int ni = 0; ni < 8; ni++)
            acc1[ni] = __builtin_amdgcn_mfma_f32_16x16x32_bf16(af, bfr[ni], acc1[ni], 0, 0, 0);
    }
    #pragma unroll
    for (int ni = 0; ni < 8; ni++) {
        int col = c0 + ni * 16 + lr;
        float bias = b1[col];
        #pragma unroll
        for (int j = 0; j < 4; j++) {
            float x = acc1[ni][j] + bias;
            float g = 0.5f * x * (1.f + erff(x * 0.70710678f));
            tl[(orow + j) * TSTRIDE + col] = f2bf(g);
        }
    }
    __syncthreads();
    // ---- FFN phase 2: 16 x 32 cols per wave, K=512 from LDS ----
    int c2 = wid * 32;
    const short* B2 = (const short*)W2T;
    f32x4_t acc2[2] = {};
    #pragma unroll 4
    for (int kc = 0; kc < 16; kc++) {
        bf16x8_t af, bfr[2];
        af = *(const bf16x8_t*)(tl + (size_t)lr * TSTRIDE + kc * 32 + lk);
        #pragma unroll
        for (int ni = 0; ni < 2; ni++)
            bfr[ni] = *(const bf16x8_t*)(B2 + (size_t)(c2 + ni * 16 + lr) * DFF + kc * 32 + lk);
        #pragma unroll
        for (int ni = 0; ni < 2; ni++)
            acc2[ni] = __builtin_amdgcn_mfma_f32_16x16x32_bf16(af, bfr[ni], acc2[ni], 0, 0, 0);
    }
    #pragma unroll
    for (int ni = 0; ni < 2; ni++) {
        int col = c2 + ni * 16 + lr;
        float bias = b2[col];
        #pragma unroll
        for (int j = 0; j < 4; j++) {
            size_t idx = (size_t)(r0 + orow + j) * D + col;
            float hn = h[idx] + acc2[ni][j] + bias;
            h[idx] = hn;
            hb[idx] = f2bf(hn);
        }
    }
}

// logits = hb(bf16 [M,128]) @ wt^T(bf16 [VOCAB,128]) -> f32 [M,VOCAB]
// R12 config restored (R13's launch_bounds(256,4) spilled: +108us — gemm
// occupancy lever closed in both directions). B tile in LDS w/ XOR swizzle,
// 4 row-bands (bg=16, 4000 blocks), bx-fastest grid, mfma(af,bfr), scalar
// NONTEMPORAL stores. ONE micro-change vs R12: store loop order mi{j{ni}}
// instead of mi{ni{j}} — each run of 4 consecutive stores now writes the
// SAME row across 64 contiguous cols (4x64B segments forming a 256B run)
// instead of alternating rows, friendlier to nt write-combining. Same
// addresses/values, pure instruction reorder -> absmax bit-identical.
__global__ __launch_bounds__(256) void k_gemm_out(const unsigned short* __restrict__ A,
                                                  const unsigned short* __restrict__ Bt,
                                                  float* __restrict__ C) {
    __shared__ unsigned short bl[128 * 128];   // 32 KB B tile
    int bx = blockIdx.x;             // VOCAB/128 = 250 (fastest)
    int bg = blockIdx.y;             // 16 band groups of 4 bands
    int tid = threadIdx.x;
    // stage B tile (contiguous 32 KB at Bt + bx*128*D) with row-XOR swizzle
    {
        const bf16x8_t* src = (const bf16x8_t*)((const short*)Bt + (size_t)bx * 128 * D);
        int row = tid >> 1;
        int base = (tid & 1) * 128;              // byte base within 256B row
        char* dst = (char*)bl + row * 256;
        #pragma unroll
        for (int i = 0; i < 8; i++) {
            int boff = base + i * 16;
            *(bf16x8_t*)(dst + (boff ^ ((row & 7) << 4))) = src[tid * 8 + i];
        }
    }
    __syncthreads();
    int wid = tid >> 6;
    int lane = tid & 63;
    int wr = wid >> 1, wc = wid & 1;
    int lr = lane & 15;
    int hi = lane >> 4;
    int lk = hi * 8;
    int col0 = bx * 128 + wc * 64;
    const short* Ap = (const short*)A;
    #pragma unroll 1
    for (int w = 0; w < 4; w++) {
        int row0 = (bg * 4 + w) * 128 + wr * 64;
        f32x4_t acc[4][4] = {};
        #pragma unroll
        for (int kc = 0; kc < 4; kc++) {
            bf16x8_t af[4], bfr[4];
            #pragma unroll
            for (int mi = 0; mi < 4; mi++)
                af[mi] = *(const bf16x8_t*)(Ap + (size_t)(row0 + mi * 16 + lr) * D + kc * 32 + lk);
            #pragma unroll
            for (int ni = 0; ni < 4; ni++) {
                int brow = wc * 64 + ni * 16 + lr;
                int boff = kc * 64 + hi * 16;
                bfr[ni] = *(const bf16x8_t*)((const char*)bl + brow * 256 + (boff ^ ((brow & 7) << 4)));
            }
            #pragma unroll
            for (int mi = 0; mi < 4; mi++)
                #pragma unroll
                for (int ni = 0; ni < 4; ni++)
                    acc[mi][ni] = __builtin_amdgcn_mfma_f32_16x16x32_bf16(af[mi], bfr[ni], acc[mi][ni], 0, 0, 0);
        }
        int orow = hi * 4;
        #pragma unroll
        for (int mi = 0; mi < 4; mi++)
            #pragma unroll
            for (int j = 0; j < 4; j++)
                #pragma unroll
                for (int ni = 0; ni < 4; ni++)
                    __builtin_nontemporal_store(acc[mi][ni][j],
                        &C[(size_t)(row0 + mi * 16 + orow + j) * VOCAB + col0 + ni * 16 + lr]);
    }
}

extern "C" void kernel_launch(void* const* d_in, const int* in_sizes, int n_in,
                              void* d_out, int out_size, void* d_ws, size_t ws_size,
                              hipStream_t stream) {
    const int*   tokens = (const int*)d_in[0];
    const float* embed  = (const float*)d_in[1];
    const float* pos    = (const float*)d_in[2];
    const float* Wq     = (const float*)d_in[3];
    const float* Wk     = (const float*)d_in[4];
    const float* Wv     = (const float*)d_in[5];
    const float* proj   = (const float*)d_in[6];
    const float* lng    = (const float*)d_in[7];
    const float* lnb    = (const float*)d_in[8];
    const float* W1     = (const float*)d_in[9];
    const float* b1     = (const float*)d_in[10];
    const float* W2     = (const float*)d_in[11];
    const float* b2     = (const float*)d_in[12];
    const float* Wout   = (const float*)d_in[13];
    float* out = (float*)d_out;
    char* ws = (char*)d_ws;

    // ws layout (MB offsets)
    float*          h    = (float*)(ws);                               // [0,4)
    unsigned short* hb   = (unsigned short*)(ws + ((size_t)4  << 20)); // [4,6)
    float*          qp   = (float*)(ws + ((size_t)6  << 20));          // [6,8)
    float*          kp   = (float*)(ws + ((size_t)8  << 20));          // [8,10)
    unsigned short* vb   = (unsigned short*)(ws + ((size_t)10 << 20)); // [10,12)
    float*          kv   = (float*)(ws + ((size_t)13 << 20));          // 64KB
    unsigned short* wt   = (unsigned short*)(ws + ((size_t)24 << 20)); // [24,32)
    unsigned short* bqkv = (unsigned short*)(ws + ((size_t)32 << 20)); // 128KB
    unsigned short* w1t  = (unsigned short*)(ws + ((size_t)33 << 20)); // 256KB
    unsigned short* w2t  = (unsigned short*)(ws + ((size_t)34 << 20)); // 256KB

    k_prep_all<<<dim3(6304), dim3(256), 0, stream>>>(tokens, embed, pos, h, hb,
                                                     Wout, wt, Wq, Wk, Wv, proj, bqkv,
                                                     W1, w1t, W2, w2t);

    for (int i = 0; i < NL; i++) {
        k_qkvp<<<dim3(M / 32), dim3(256), 0, stream>>>(hb, bqkv + (size_t)i * 256 * D, qp, kp, vb, kv);
        k_kvpart<<<dim3(P, 16, BATCH), dim3(128), 0, stream>>>(kp, vb, kv);
        k_attnffn<<<dim3(M / 16), dim3(256), 0, stream>>>(qp, kv, lng + (size_t)i * D, lnb + (size_t)i * D,
                                                          w1t + (size_t)i * DFF * D, b1 + (size_t)i * DFF,
                                                          w2t + (size_t)i * D * DFF, b2 + (size_t)i * D, h, hb);
    }

    k_gemm_out<<<dim3(VOCAB / 128, M / 128 / 4), dim3(256), 0, stream>>>(hb, wt, out);
}

// Round 15
// 341.130 us; speedup vs baseline: 1.4952x; 1.0720x over previous
//
#include <hip/hip_runtime.h>
#include <hip/hip_bf16.h>

#define BATCH 2
#define LSEQ 4096
#define M (BATCH*LSEQ)   // 8192 rows
#define D 128
#define P 64
#define NL 2
#define VOCAB 32000
#define DFF 512

typedef __attribute__((ext_vector_type(8))) short bf16x8_t;
typedef __attribute__((ext_vector_type(4))) float f32x4_t;

__device__ inline unsigned short f2bf(float f) {
    unsigned int u = __float_as_uint(f);
    unsigned int r = (u + 0x7fffu + ((u >> 16) & 1u)) >> 16;
    return (unsigned short)r;
}
__device__ inline float bf2f(unsigned short u) {
    return __uint_as_float(((unsigned int)u) << 16);
}

// Fused prologue: all 5 prep kernels as disjoint block ranges of ONE dispatch
// (R10: -10us). Section math byte-identical to the unfused kernels.
//  [0,1024)      embed: h/hb
//  [1024,5024)   Wout -> wt transpose
//  [5024,5280)   bqkv (WqpT/WkpT/WvT)
//  [5280,5792)   W1T
//  [5792,6304)   W2T
__global__ __launch_bounds__(256) void k_prep_all(const int* __restrict__ tokens,
                                                  const float* __restrict__ embed,
                                                  const float* __restrict__ pos,
                                                  float* __restrict__ h,
                                                  unsigned short* __restrict__ hb,
                                                  const float* __restrict__ Wout,
                                                  unsigned short* __restrict__ WT,
                                                  const float* __restrict__ Wq,
                                                  const float* __restrict__ Wk,
                                                  const float* __restrict__ Wv,
                                                  const float* __restrict__ proj,
                                                  unsigned short* __restrict__ bqkv,
                                                  const float* __restrict__ W1,
                                                  unsigned short* __restrict__ W1T,
                                                  const float* __restrict__ W2,
                                                  unsigned short* __restrict__ W2T) {
    __shared__ float tile[32][33];
    int b = blockIdx.x;
    int tid = threadIdx.x;
    if (b < 1024) {
        // ---- embed ----
        int gid = b * 256 + tid;               // over M*32 float4s
        int row = gid >> 5;
        int d4  = gid & 31;
        int l = row & (LSEQ - 1);
        int tok = tokens[row];
        float4 a = ((const float4*)(embed + (size_t)tok * D))[d4];
        float4 p4 = ((const float4*)(pos + (size_t)l * D))[d4];
        a.x += p4.x; a.y += p4.y; a.z += p4.z; a.w += p4.w;
        ((float4*)(h + (size_t)row * D))[d4] = a;
        ushort4 u; u.x = f2bf(a.x); u.y = f2bf(a.y); u.z = f2bf(a.z); u.w = f2bf(a.w);
        ((ushort4*)(hb + (size_t)row * D))[d4] = u;
    } else if (b < 5024) {
        // ---- Wout transpose ----
        int bb = b - 1024;
        int v0 = (bb % 1000) * 32, d0 = (bb / 1000) * 32;
        int tx = tid & 31, ty = tid >> 5;
        for (int i = ty; i < 32; i += 8)
            tile[i][tx] = Wout[(size_t)(d0 + i) * VOCAB + v0 + tx];
        __syncthreads();
        for (int i = ty; i < 32; i += 8)
            WT[(size_t)(v0 + i) * D + d0 + tx] = f2bf(tile[tx][i]);
    } else if (b < 5280) {
        // ---- bqkv ----
        int idx = (b - 5024) * 256 + tid;      // 2*256*128
        int d = idx & 127;
        int r = (idx >> 7) & 255;
        int l = idx >> 15;
        const float* WqL = Wq + (size_t)l * D * D;
        const float* WkL = Wk + (size_t)l * D * D;
        const float* WvL = Wv + (size_t)l * D * D;
        const float* pjL = proj + (size_t)l * D * P;
        float val;
        if (r < 128) {
            const float* W = (r < 64) ? WqL : WkL;
            int p = r & 63;
            float s = 0.f;
            for (int e = 0; e < D; e++) s = fmaf(W[d * D + e], pjL[e * P + p], s);
            val = s;
        } else {
            val = WvL[d * D + (r - 128)];
        }
        bqkv[((size_t)l * 256 + r) * D + d] = f2bf(val);
    } else if (b < 5792) {
        // ---- W1T ----
        int idx = (b - 5280) * 256 + tid;      // 2*512*128
        int d = idx & 127;
        int n = (idx >> 7) & 511;
        int l = idx >> 16;
        W1T[((size_t)l * DFF + n) * D + d] = f2bf(W1[((size_t)l * D + d) * DFF + n]);
    } else {
        // ---- W2T ----
        int idx = (b - 5792) * 256 + tid;      // 2*128*512
        int f = idx & 511;
        int n = (idx >> 9) & 127;
        int l = idx >> 16;
        W2T[((size_t)l * D + n) * DFF + f] = f2bf(W2[((size_t)l * DFF + f) * D + n]);
    }
}

// Fused projections: C[M x 256] = hb @ BqkvT^T ; cols 0-63 -> qp=elu(x)+1 (f32),
// 64-127 -> kp (f32), 128-255 -> vb (bf16). Tile 32 rows x 256 cols, 4 waves.
// Block 0 additionally zeroes kv for this layer (consumed by kvpart's atomics;
// safe: attnffn of the previous layer finished at the kernel boundary).
// R11 LESSON: __threadfence() inside a kernel = device-scope release on
// non-coherent per-XCD L2s = L2 writeback per block (-166us!). Cross-block
// dataflow must use kernel boundaries or atomics (G12/m20: cheap), never fences.
__global__ __launch_bounds__(256) void k_qkvp(const unsigned short* __restrict__ hb,
                                              const unsigned short* __restrict__ Bt,
                                              float* __restrict__ qp, float* __restrict__ kp,
                                              unsigned short* __restrict__ vb,
                                              float* __restrict__ kv) {
    if (blockIdx.x == 0) {   // zero kv (BATCH*P*D f32 = 64KB) for atomic accumulation
        float4 z = make_float4(0.f, 0.f, 0.f, 0.f);
        float4* kv4 = (float4*)kv;
        for (int i = threadIdx.x; i < BATCH * P * D / 4; i += 256) kv4[i] = z;
    }
    int r0 = blockIdx.x * 32;
    int wid = threadIdx.x >> 6;
    int lane = threadIdx.x & 63;
    int c0 = wid * 64;
    int lr = lane & 15;
    int lk = (lane >> 4) * 8;
    const short* Ap = (const short*)hb;
    const short* Bp = (const short*)Bt;
    f32x4_t acc[2][4] = {};
    #pragma unroll
    for (int kc = 0; kc < 4; kc++) {
        bf16x8_t af[2], bfr[4];
        #pragma unroll
        for (int mi = 0; mi < 2; mi++)
            af[mi] = *(const bf16x8_t*)(Ap + (size_t)(r0 + mi * 16 + lr) * D + kc * 32 + lk);
        #pragma unroll
        for (int ni = 0; ni < 4; ni++)
            bfr[ni] = *(const bf16x8_t*)(Bp + (size_t)(c0 + ni * 16 + lr) * D + kc * 32 + lk);
        #pragma unroll
        for (int mi = 0; mi < 2; mi++)
            #pragma unroll
            for (int ni = 0; ni < 4; ni++)
                acc[mi][ni] = __builtin_amdgcn_mfma_f32_16x16x32_bf16(af[mi], bfr[ni], acc[mi][ni], 0, 0, 0);
    }
    int orow = (lane >> 4) * 4;
    if (wid < 2) {  // qp / kp with elu(x)+1, f32 out
        float* out = (wid == 0) ? qp : kp;
        #pragma unroll
        for (int mi = 0; mi < 2; mi++)
            #pragma unroll
            for (int ni = 0; ni < 4; ni++)
                #pragma unroll
                for (int j = 0; j < 4; j++) {
                    float x = acc[mi][ni][j];
                    float e = x > 0.f ? x + 1.f : __expf(x);
                    out[(size_t)(r0 + mi * 16 + orow + j) * P + ni * 16 + lr] = e;
                }
    } else {        // vb bf16 out, cols (wid-2)*64 + ...
        int cb = (wid - 2) * 64;
        #pragma unroll
        for (int mi = 0; mi < 2; mi++)
            #pragma unroll
            for (int ni = 0; ni < 4; ni++)
                #pragma unroll
                for (int j = 0; j < 4; j++)
                    vb[(size_t)(r0 + mi * 16 + orow + j) * D + cb + ni * 16 + lr] = f2bf(acc[mi][ni][j]);
    }
}

// partial kv, accumulated straight into kv via device-scope atomicAdd
// (replaces part buffer + kvred kernel; no fences — atomics execute at the
// device-coherent point without L2 flush). 16-way per-address contention,
// ~1MB total RMW traffic. Summation order of the 16 chunk partials becomes
// nondeterministic: f32 reshuffle of 16 terms, ~ulp-scale, benign.
__global__ void k_kvpart(const float* __restrict__ kp, const unsigned short* __restrict__ vb,
                         float* __restrict__ kv) {
    int p = blockIdx.x, ch = blockIdx.y, b = blockIdx.z, d = threadIdx.x;
    const float* kpb = kp + (size_t)b * LSEQ * P + p;
    const unsigned short* vbp = vb + (size_t)b * LSEQ * D + d;
    int l0 = ch * 256;
    float a0 = 0.f, a1 = 0.f, a2 = 0.f, a3 = 0.f;
    for (int l = l0; l < l0 + 256; l += 4) {
        a0 = fmaf(kpb[(size_t)l * P],       bf2f(vbp[(size_t)l * D]),       a0);
        a1 = fmaf(kpb[(size_t)(l + 1) * P], bf2f(vbp[(size_t)(l + 1) * D]), a1);
        a2 = fmaf(kpb[(size_t)(l + 2) * P], bf2f(vbp[(size_t)(l + 2) * D]), a2);
        a3 = fmaf(kpb[(size_t)(l + 3) * P], bf2f(vbp[(size_t)(l + 3) * D]), a3);
    }
    atomicAdd(&kv[((size_t)b * P + p) * D + d], (a0 + a1) + (a2 + a3));
}

// Fused attn + LN + FFN per 16-row tile:
//   attn = (qp @ kv) / (sum_p qp + eps)
//   a    = layernorm(attn)*g + b          -> bf16 tile in LDS (stride 136)
//   h   += gelu(a @ W1T^T + b1) @ W2T^T + b2; hb = bf16(h)
// attn/LN thread layout: row = tid>>4 (16 rows), 8 d-elems per thread;
// LN reduction = pure 16-lane shfl_xor tree (no LDS, no barriers).
#define TSTRIDE 520
#define ABSTRIDE 136
__global__ __launch_bounds__(256) void k_attnffn(const float* __restrict__ qp,
                                                 const float* __restrict__ kv,
                                                 const float* __restrict__ lng,
                                                 const float* __restrict__ lnb,
                                                 const unsigned short* __restrict__ W1T,
                                                 const float* __restrict__ b1,
                                                 const unsigned short* __restrict__ W2T,
                                                 const float* __restrict__ b2,
                                                 float* __restrict__ h,
                                                 unsigned short* __restrict__ hb) {
    __shared__ unsigned short abt[16 * ABSTRIDE];  // 4.4 KB
    __shared__ unsigned short tl[16 * TSTRIDE];    // 16.6 KB
    int r0 = blockIdx.x * 16;
    int b = r0 >> 12;
    int tid = threadIdx.x;
    // ---- attn + LN: row = tid>>4, d0 = (tid&15)*8 ----
    {
        int row16 = tid >> 4;
        int dq = tid & 15;
        int d0 = dq * 8;
        const float* qpr = qp + (size_t)(r0 + row16) * P;
        const float4* kv4 = (const float4*)(kv + (size_t)b * P * D);
        float num[8] = {};
        float zs = 0.f;
        #pragma unroll 8
        for (int p = 0; p < P; p++) {
            float qv = qpr[p];
            zs += qv;
            float4 v0 = kv4[p * 32 + dq * 2];
            float4 v1 = kv4[p * 32 + dq * 2 + 1];
            num[0] = fmaf(qv, v0.x, num[0]);
            num[1] = fmaf(qv, v0.y, num[1]);
            num[2] = fmaf(qv, v0.z, num[2]);
            num[3] = fmaf(qv, v0.w, num[3]);
            num[4] = fmaf(qv, v1.x, num[4]);
            num[5] = fmaf(qv, v1.y, num[5]);
            num[6] = fmaf(qv, v1.z, num[6]);
            num[7] = fmaf(qv, v1.w, num[7]);
        }
        float rz = 1.f / (zs + 1e-8f);
        float attn[8];
        float s = 0.f;
        #pragma unroll
        for (int j = 0; j < 8; j++) { attn[j] = num[j] * rz; s += attn[j]; }
        #pragma unroll
        for (int m = 1; m < 16; m <<= 1) s += __shfl_xor(s, m);
        float mu = s * (1.f / 128.f);
        float dv[8];
        float s2 = 0.f;
        #pragma unroll
        for (int j = 0; j < 8; j++) { dv[j] = attn[j] - mu; s2 = fmaf(dv[j], dv[j], s2); }
        #pragma unroll
        for (int m = 1; m < 16; m <<= 1) s2 += __shfl_xor(s2, m);
        float rs = rsqrtf(s2 * (1.f / 128.f) + 1e-5f);
        #pragma unroll
        for (int j = 0; j < 8; j++) {
            float o = dv[j] * rs * lng[d0 + j] + lnb[d0 + j];
            abt[row16 * ABSTRIDE + d0 + j] = f2bf(o);
        }
    }
    __syncthreads();
    // ---- FFN phase 1: 16 x 128 cols per wave, K=128, A from LDS ----
    int wid = tid >> 6;
    int lane = tid & 63;
    int lr = lane & 15;
    int lk = (lane >> 4) * 8;
    int orow = (lane >> 4) * 4;
    const short* B1 = (const short*)W1T;
    int c0 = wid * 128;
    f32x4_t acc1[8] = {};
    #pragma unroll
    for (int kc = 0; kc < 4; kc++) {
        bf16x8_t af = *(const bf16x8_t*)(abt + lr * ABSTRIDE + kc * 32 + lk);
        bf16x8_t bfr[8];
        #pragma unroll
        for (int ni = 0; ni < 8; ni++)
            bfr[ni] = *(const bf16x8_t*)(B1 + (size_t)(c0 + ni * 16 + lr) * D + kc * 32 + lk);
        #pragma unroll
        for (int ni = 0; ni < 8; ni++)
            acc1[ni] = __builtin_amdgcn_mfma_f32_16x16x32_bf16(af, bfr[ni], acc1[ni], 0, 0, 0);
    }
    #pragma unroll
    for (int ni = 0; ni < 8; ni++) {
        int col = c0 + ni * 16 + lr;
        float bias = b1[col];
        #pragma unroll
        for (int j = 0; j < 4; j++) {
            float x = acc1[ni][j] + bias;
            float g = 0.5f * x * (1.f + erff(x * 0.70710678f));
            tl[(orow + j) * TSTRIDE + col] = f2bf(g);
        }
    }
    __syncthreads();
    // ---- FFN phase 2: 16 x 32 cols per wave, K=512 from LDS ----
    int c2 = wid * 32;
    const short* B2 = (const short*)W2T;
    f32x4_t acc2[2] = {};
    #pragma unroll 4
    for (int kc = 0; kc < 16; kc++) {
        bf16x8_t af, bfr[2];
        af = *(const bf16x8_t*)(tl + (size_t)lr * TSTRIDE + kc * 32 + lk);
        #pragma unroll
        for (int ni = 0; ni < 2; ni++)
            bfr[ni] = *(const bf16x8_t*)(B2 + (size_t)(c2 + ni * 16 + lr) * DFF + kc * 32 + lk);
        #pragma unroll
        for (int ni = 0; ni < 2; ni++)
            acc2[ni] = __builtin_amdgcn_mfma_f32_16x16x32_bf16(af, bfr[ni], acc2[ni], 0, 0, 0);
    }
    #pragma unroll
    for (int ni = 0; ni < 2; ni++) {
        int col = c2 + ni * 16 + lr;
        float bias = b2[col];
        #pragma unroll
        for (int j = 0; j < 4; j++) {
            size_t idx = (size_t)(r0 + orow + j) * D + col;
            float hn = h[idx] + acc2[ni][j] + bias;
            h[idx] = hn;
            hb[idx] = f2bf(hn);
        }
    }
}

// logits = hb(bf16 [M,128]) @ wt^T(bf16 [VOCAB,128]) -> f32 [M,VOCAB]
// R14 structure (B tile LDS + XOR swizzle, 4 bands, bg=16, bx-fastest,
// mfma(af,bfr), NT stores, row-run store order: -36us in R14 — nt bypasses
// L2 so HBM burst shape matters; same-row runs let WC merge 64B->256B).
// ONE change vs R14: LDS-staged 512B-burst epilogue. Per band, 4 rounds of
// {stage 32 rows (16.9KB, stride 132 f32: 2-way max on writes, 16B-aligned
// f32x4 reads) -> all 4 waves cooperatively nt-store f32x4: each instruction
// = 2 rows x 512B physically contiguous}. Store instrs 64 -> 16/thread.
// LDS 32KB+16.9KB = 49.7KB -> still 3 blocks/CU (R7's 65KB dropped to 2).
// Values pass through LDS as exact f32 -> absmax bit-identical.
__global__ __launch_bounds__(256) void k_gemm_out(const unsigned short* __restrict__ A,
                                                  const unsigned short* __restrict__ Bt,
                                                  float* __restrict__ C) {
    __shared__ unsigned short bl[128 * 128];   // 32 KB B tile
    __shared__ float cl[32 * 132];             // 16.9 KB C stage (32 rows)
    int bx = blockIdx.x;             // VOCAB/128 = 250 (fastest)
    int bg = blockIdx.y;             // 16 band groups of 4 bands
    int tid = threadIdx.x;
    // stage B tile (contiguous 32 KB at Bt + bx*128*D) with row-XOR swizzle
    {
        const bf16x8_t* src = (const bf16x8_t*)((const short*)Bt + (size_t)bx * 128 * D);
        int row = tid >> 1;
        int base = (tid & 1) * 128;              // byte base within 256B row
        char* dst = (char*)bl + row * 256;
        #pragma unroll
        for (int i = 0; i < 8; i++) {
            int boff = base + i * 16;
            *(bf16x8_t*)(dst + (boff ^ ((row & 7) << 4))) = src[tid * 8 + i];
        }
    }
    __syncthreads();
    int wid = tid >> 6;
    int lane = tid & 63;
    int wr = wid >> 1, wc = wid & 1;
    int lr = lane & 15;
    int hi = lane >> 4;
    int lk = hi * 8;
    const short* Ap = (const short*)A;
    #pragma unroll 1
    for (int w = 0; w < 4; w++) {
        int row0b = (bg * 4 + w) * 128;
        int row0 = row0b + wr * 64;
        f32x4_t acc[4][4] = {};
        #pragma unroll
        for (int kc = 0; kc < 4; kc++) {
            bf16x8_t af[4], bfr[4];
            #pragma unroll
            for (int mi = 0; mi < 4; mi++)
                af[mi] = *(const bf16x8_t*)(Ap + (size_t)(row0 + mi * 16 + lr) * D + kc * 32 + lk);
            #pragma unroll
            for (int ni = 0; ni < 4; ni++) {
                int brow = wc * 64 + ni * 16 + lr;
                int boff = kc * 64 + hi * 16;
                bfr[ni] = *(const bf16x8_t*)((const char*)bl + brow * 256 + (boff ^ ((brow & 7) << 4)));
            }
            #pragma unroll
            for (int mi = 0; mi < 4; mi++)
                #pragma unroll
                for (int ni = 0; ni < 4; ni++)
                    acc[mi][ni] = __builtin_amdgcn_mfma_f32_16x16x32_bf16(af[mi], bfr[ni], acc[mi][ni], 0, 0, 0);
        }
        // LDS-staged epilogue: 4 rounds of 32 rows
        #pragma unroll
        for (int r = 0; r < 4; r++) {
            __syncthreads();   // previous round's cooperative reads done
            if (wr == (r >> 1)) {
                #pragma unroll
                for (int mi2 = 0; mi2 < 2; mi2++) {
                    int mi = (r & 1) * 2 + mi2;
                    #pragma unroll
                    for (int ni = 0; ni < 4; ni++)
                        #pragma unroll
                        for (int j = 0; j < 4; j++)
                            cl[(mi2 * 16 + hi * 4 + j) * 132 + wc * 64 + ni * 16 + lr] = acc[mi][ni][j];
                }
            }
            __syncthreads();
            // cooperative nt store: 32 rows x 128 f32; per instruction a wave
            // writes 2 rows x 512B contiguous.
            float* Cb = C + (size_t)(row0b + r * 32) * VOCAB + bx * 128;
            #pragma unroll
            for (int k = 0; k < 4; k++) {
                int idx = k * 256 + tid;
                int rr = idx >> 5;
                int c4 = idx & 31;
                f32x4_t v = *(const f32x4_t*)(cl + rr * 132 + c4 * 4);
                __builtin_nontemporal_store(v, (f32x4_t*)(Cb + (size_t)rr * VOCAB + c4 * 4));
            }
        }
    }
}

extern "C" void kernel_launch(void* const* d_in, const int* in_sizes, int n_in,
                              void* d_out, int out_size, void* d_ws, size_t ws_size,
                              hipStream_t stream) {
    const int*   tokens = (const int*)d_in[0];
    const float* embed  = (const float*)d_in[1];
    const float* pos    = (const float*)d_in[2];
    const float* Wq     = (const float*)d_in[3];
    const float* Wk     = (const float*)d_in[4];
    const float* Wv     = (const float*)d_in[5];
    const float* proj   = (const float*)d_in[6];
    const float* lng    = (const float*)d_in[7];
    const float* lnb    = (const float*)d_in[8];
    const float* W1     = (const float*)d_in[9];
    const float* b1     = (const float*)d_in[10];
    const float* W2     = (const float*)d_in[11];
    const float* b2     = (const float*)d_in[12];
    const float* Wout   = (const float*)d_in[13];
    float* out = (float*)d_out;
    char* ws = (char*)d_ws;

    // ws layout (MB offsets)
    float*          h    = (float*)(ws);                               // [0,4)
    unsigned short* hb   = (unsigned short*)(ws + ((size_t)4  << 20)); // [4,6)
    float*          qp   = (float*)(ws + ((size_t)6  << 20));          // [6,8)
    float*          kp   = (float*)(ws + ((size_t)8  << 20));          // [8,10)
    unsigned short* vb   = (unsigned short*)(ws + ((size_t)10 << 20)); // [10,12)
    float*          kv   = (float*)(ws + ((size_t)13 << 20));          // 64KB
    unsigned short* wt   = (unsigned short*)(ws + ((size_t)24 << 20)); // [24,32)
    unsigned short* bqkv = (unsigned short*)(ws + ((size_t)32 << 20)); // 128KB
    unsigned short* w1t  = (unsigned short*)(ws + ((size_t)33 << 20)); // 256KB
    unsigned short* w2t  = (unsigned short*)(ws + ((size_t)34 << 20)); // 256KB

    k_prep_all<<<dim3(6304), dim3(256), 0, stream>>>(tokens, embed, pos, h, hb,
                                                     Wout, wt, Wq, Wk, Wv, proj, bqkv,
                                                     W1, w1t, W2, w2t);

    for (int i = 0; i < NL; i++) {
        k_qkvp<<<dim3(M / 32), dim3(256), 0, stream>>>(hb, bqkv + (size_t)i * 256 * D, qp, kp, vb, kv);
        k_kvpart<<<dim3(P, 16, BATCH), dim3(128), 0, stream>>>(kp, vb, kv);
        k_attnffn<<<dim3(M / 16), dim3(256), 0, stream>>>(qp, kv, lng + (size_t)i * D, lnb + (size_t)i * D,
                                                          w1t + (size_t)i * DFF * D, b1 + (size_t)i * DFF,
                                                          w2t + (size_t)i * D * DFF, b2 + (size_t)i * D, h, hb);
    }

    k_gemm_out<<<dim3(VOCAB / 128, M / 128 / 4), dim3(256), 0, stream>>>(hb, wt, out);
}

// Round 17
// 329.301 us; speedup vs baseline: 1.5489x; 1.0359x over previous
//
#include <hip/hip_runtime.h>
#include <hip/hip_bf16.h>

#define BATCH 2
#define LSEQ 4096
#define M (BATCH*LSEQ)   // 8192 rows
#define D 128
#define P 64
#define NL 2
#define VOCAB 32000
#define DFF 512

typedef __attribute__((ext_vector_type(8))) short bf16x8_t;
typedef __attribute__((ext_vector_type(4))) float f32x4_t;

__device__ inline unsigned short f2bf(float f) {
    unsigned int u = __float_as_uint(f);
    unsigned int r = (u + 0x7fffu + ((u >> 16) & 1u)) >> 16;
    return (unsigned short)r;
}
__device__ inline float bf2f(unsigned short u) {
    return __uint_as_float(((unsigned int)u) << 16);
}

// Fused prologue: all 5 prep kernels as disjoint block ranges of ONE dispatch
// (R10: -10us). Section math byte-identical to the unfused kernels.
//  [0,1024)      embed: h/hb
//  [1024,5024)   Wout -> wt transpose
//  [5024,5280)   bqkv (WqpT/WkpT/WvT)
//  [5280,5792)   W1T
//  [5792,6304)   W2T
__global__ __launch_bounds__(256) void k_prep_all(const int* __restrict__ tokens,
                                                  const float* __restrict__ embed,
                                                  const float* __restrict__ pos,
                                                  float* __restrict__ h,
                                                  unsigned short* __restrict__ hb,
                                                  const float* __restrict__ Wout,
                                                  unsigned short* __restrict__ WT,
                                                  const float* __restrict__ Wq,
                                                  const float* __restrict__ Wk,
                                                  const float* __restrict__ Wv,
                                                  const float* __restrict__ proj,
                                                  unsigned short* __restrict__ bqkv,
                                                  const float* __restrict__ W1,
                                                  unsigned short* __restrict__ W1T,
                                                  const float* __restrict__ W2,
                                                  unsigned short* __restrict__ W2T) {
    __shared__ float tile[32][33];
    int b = blockIdx.x;
    int tid = threadIdx.x;
    if (b < 1024) {
        // ---- embed ----
        int gid = b * 256 + tid;               // over M*32 float4s
        int row = gid >> 5;
        int d4  = gid & 31;
        int l = row & (LSEQ - 1);
        int tok = tokens[row];
        float4 a = ((const float4*)(embed + (size_t)tok * D))[d4];
        float4 p4 = ((const float4*)(pos + (size_t)l * D))[d4];
        a.x += p4.x; a.y += p4.y; a.z += p4.z; a.w += p4.w;
        ((float4*)(h + (size_t)row * D))[d4] = a;
        ushort4 u; u.x = f2bf(a.x); u.y = f2bf(a.y); u.z = f2bf(a.z); u.w = f2bf(a.w);
        ((ushort4*)(hb + (size_t)row * D))[d4] = u;
    } else if (b < 5024) {
        // ---- Wout transpose ----
        int bb = b - 1024;
        int v0 = (bb % 1000) * 32, d0 = (bb / 1000) * 32;
        int tx = tid & 31, ty = tid >> 5;
        for (int i = ty; i < 32; i += 8)
            tile[i][tx] = Wout[(size_t)(d0 + i) * VOCAB + v0 + tx];
        __syncthreads();
        for (int i = ty; i < 32; i += 8)
            WT[(size_t)(v0 + i) * D + d0 + tx] = f2bf(tile[tx][i]);
    } else if (b < 5280) {
        // ---- bqkv ----
        int idx = (b - 5024) * 256 + tid;      // 2*256*128
        int d = idx & 127;
        int r = (idx >> 7) & 255;
        int l = idx >> 15;
        const float* WqL = Wq + (size_t)l * D * D;
        const float* WkL = Wk + (size_t)l * D * D;
        const float* WvL = Wv + (size_t)l * D * D;
        const float* pjL = proj + (size_t)l * D * P;
        float val;
        if (r < 128) {
            const float* W = (r < 64) ? WqL : WkL;
            int p = r & 63;
            float s = 0.f;
            for (int e = 0; e < D; e++) s = fmaf(W[d * D + e], pjL[e * P + p], s);
            val = s;
        } else {
            val = WvL[d * D + (r - 128)];
        }
        bqkv[((size_t)l * 256 + r) * D + d] = f2bf(val);
    } else if (b < 5792) {
        // ---- W1T ----
        int idx = (b - 5280) * 256 + tid;      // 2*512*128
        int d = idx & 127;
        int n = (idx >> 7) & 511;
        int l = idx >> 16;
        W1T[((size_t)l * DFF + n) * D + d] = f2bf(W1[((size_t)l * D + d) * DFF + n]);
    } else {
        // ---- W2T ----
        int idx = (b - 5792) * 256 + tid;      // 2*128*512
        int f = idx & 511;
        int n = (idx >> 9) & 127;
        int l = idx >> 16;
        W2T[((size_t)l * D + n) * DFF + f] = f2bf(W2[((size_t)l * DFF + f) * D + n]);
    }
}

// Fused projections: C[M x 256] = hb @ BqkvT^T ; cols 0-63 -> qp=elu(x)+1 (f32),
// 64-127 -> kp (f32), 128-255 -> vb (bf16). Tile 32 rows x 256 cols, 4 waves.
// Block 0 additionally zeroes kv for this layer (consumed by kvpart's atomics;
// safe: attnffn of the previous layer finished at the kernel boundary).
// R11 LESSON: __threadfence() inside a kernel = device-scope release on
// non-coherent per-XCD L2s = L2 writeback per block (-166us!). Cross-block
// dataflow must use kernel boundaries or atomics (G12/m20: cheap), never fences.
__global__ __launch_bounds__(256) void k_qkvp(const unsigned short* __restrict__ hb,
                                              const unsigned short* __restrict__ Bt,
                                              float* __restrict__ qp, float* __restrict__ kp,
                                              unsigned short* __restrict__ vb,
                                              float* __restrict__ kv) {
    if (blockIdx.x == 0) {   // zero kv (BATCH*P*D f32 = 64KB) for atomic accumulation
        float4 z = make_float4(0.f, 0.f, 0.f, 0.f);
        float4* kv4 = (float4*)kv;
        for (int i = threadIdx.x; i < BATCH * P * D / 4; i += 256) kv4[i] = z;
    }
    int r0 = blockIdx.x * 32;
    int wid = threadIdx.x >> 6;
    int lane = threadIdx.x & 63;
    int c0 = wid * 64;
    int lr = lane & 15;
    int lk = (lane >> 4) * 8;
    const short* Ap = (const short*)hb;
    const short* Bp = (const short*)Bt;
    f32x4_t acc[2][4] = {};
    #pragma unroll
    for (int kc = 0; kc < 4; kc++) {
        bf16x8_t af[2], bfr[4];
        #pragma unroll
        for (int mi = 0; mi < 2; mi++)
            af[mi] = *(const bf16x8_t*)(Ap + (size_t)(r0 + mi * 16 + lr) * D + kc * 32 + lk);
        #pragma unroll
        for (int ni = 0; ni < 4; ni++)
            bfr[ni] = *(const bf16x8_t*)(Bp + (size_t)(c0 + ni * 16 + lr) * D + kc * 32 + lk);
        #pragma unroll
        for (int mi = 0; mi < 2; mi++)
            #pragma unroll
            for (int ni = 0; ni < 4; ni++)
                acc[mi][ni] = __builtin_amdgcn_mfma_f32_16x16x32_bf16(af[mi], bfr[ni], acc[mi][ni], 0, 0, 0);
    }
    int orow = (lane >> 4) * 4;
    if (wid < 2) {  // qp / kp with elu(x)+1, f32 out
        float* out = (wid == 0) ? qp : kp;
        #pragma unroll
        for (int mi = 0; mi < 2; mi++)
            #pragma unroll
            for (int ni = 0; ni < 4; ni++)
                #pragma unroll
                for (int j = 0; j < 4; j++) {
                    float x = acc[mi][ni][j];
                    float e = x > 0.f ? x + 1.f : __expf(x);
                    out[(size_t)(r0 + mi * 16 + orow + j) * P + ni * 16 + lr] = e;
                }
    } else {        // vb bf16 out, cols (wid-2)*64 + ...
        int cb = (wid - 2) * 64;
        #pragma unroll
        for (int mi = 0; mi < 2; mi++)
            #pragma unroll
            for (int ni = 0; ni < 4; ni++)
                #pragma unroll
                for (int j = 0; j < 4; j++)
                    vb[(size_t)(r0 + mi * 16 + orow + j) * D + cb + ni * 16 + lr] = f2bf(acc[mi][ni][j]);
    }
}

// partial kv, accumulated straight into kv via device-scope atomicAdd
// (replaces part buffer + kvred kernel; no fences — atomics execute at the
// device-coherent point without L2 flush). 16-way per-address contention,
// ~1MB total RMW traffic. Summation order of the 16 chunk partials becomes
// nondeterministic: f32 reshuffle of 16 terms, ~ulp-scale, benign.
__global__ void k_kvpart(const float* __restrict__ kp, const unsigned short* __restrict__ vb,
                         float* __restrict__ kv) {
    int p = blockIdx.x, ch = blockIdx.y, b = blockIdx.z, d = threadIdx.x;
    const float* kpb = kp + (size_t)b * LSEQ * P + p;
    const unsigned short* vbp = vb + (size_t)b * LSEQ * D + d;
    int l0 = ch * 256;
    float a0 = 0.f, a1 = 0.f, a2 = 0.f, a3 = 0.f;
    for (int l = l0; l < l0 + 256; l += 4) {
        a0 = fmaf(kpb[(size_t)l * P],       bf2f(vbp[(size_t)l * D]),       a0);
        a1 = fmaf(kpb[(size_t)(l + 1) * P], bf2f(vbp[(size_t)(l + 1) * D]), a1);
        a2 = fmaf(kpb[(size_t)(l + 2) * P], bf2f(vbp[(size_t)(l + 2) * D]), a2);
        a3 = fmaf(kpb[(size_t)(l + 3) * P], bf2f(vbp[(size_t)(l + 3) * D]), a3);
    }
    atomicAdd(&kv[((size_t)b * P + p) * D + d], (a0 + a1) + (a2 + a3));
}

// Fused attn + LN + FFN per 16-row tile:
//   attn = (qp @ kv) / (sum_p qp + eps)
//   a    = layernorm(attn)*g + b          -> bf16 tile in LDS (stride 136)
//   h   += gelu(a @ W1T^T + b1) @ W2T^T + b2; hb = bf16(h)
// attn/LN thread layout: row = tid>>4 (16 rows), 8 d-elems per thread;
// LN reduction = pure 16-lane shfl_xor tree (no LDS, no barriers).
#define TSTRIDE 520
#define ABSTRIDE 136
__global__ __launch_bounds__(256) void k_attnffn(const float* __restrict__ qp,
                                                 const float* __restrict__ kv,
                                                 const float* __restrict__ lng,
                                                 const float* __restrict__ lnb,
                                                 const unsigned short* __restrict__ W1T,
                                                 const float* __restrict__ b1,
                                                 const unsigned short* __restrict__ W2T,
                                                 const float* __restrict__ b2,
                                                 float* __restrict__ h,
                                                 unsigned short* __restrict__ hb) {
    __shared__ unsigned short abt[16 * ABSTRIDE];  // 4.4 KB
    __shared__ unsigned short tl[16 * TSTRIDE];    // 16.6 KB
    int r0 = blockIdx.x * 16;
    int b = r0 >> 12;
    int tid = threadIdx.x;
    // ---- attn + LN: row = tid>>4, d0 = (tid&15)*8 ----
    {
        int row16 = tid >> 4;
        int dq = tid & 15;
        int d0 = dq * 8;
        const float* qpr = qp + (size_t)(r0 + row16) * P;
        const float4* kv4 = (const float4*)(kv + (size_t)b * P * D);
        float num[8] = {};
        float zs = 0.f;
        #pragma unroll 8
        for (int p = 0; p < P; p++) {
            float qv = qpr[p];
            zs += qv;
            float4 v0 = kv4[p * 32 + dq * 2];
            float4 v1 = kv4[p * 32 + dq * 2 + 1];
            num[0] = fmaf(qv, v0.x, num[0]);
            num[1] = fmaf(qv, v0.y, num[1]);
            num[2] = fmaf(qv, v0.z, num[2]);
            num[3] = fmaf(qv, v0.w, num[3]);
            num[4] = fmaf(qv, v1.x, num[4]);
            num[5] = fmaf(qv, v1.y, num[5]);
            num[6] = fmaf(qv, v1.z, num[6]);
            num[7] = fmaf(qv, v1.w, num[7]);
        }
        float rz = 1.f / (zs + 1e-8f);
        float attn[8];
        float s = 0.f;
        #pragma unroll
        for (int j = 0; j < 8; j++) { attn[j] = num[j] * rz; s += attn[j]; }
        #pragma unroll
        for (int m = 1; m < 16; m <<= 1) s += __shfl_xor(s, m);
        float mu = s * (1.f / 128.f);
        float dv[8];
        float s2 = 0.f;
        #pragma unroll
        for (int j = 0; j < 8; j++) { dv[j] = attn[j] - mu; s2 = fmaf(dv[j], dv[j], s2); }
        #pragma unroll
        for (int m = 1; m < 16; m <<= 1) s2 += __shfl_xor(s2, m);
        float rs = rsqrtf(s2 * (1.f / 128.f) + 1e-5f);
        #pragma unroll
        for (int j = 0; j < 8; j++) {
            float o = dv[j] * rs * lng[d0 + j] + lnb[d0 + j];
            abt[row16 * ABSTRIDE + d0 + j] = f2bf(o);
        }
    }
    __syncthreads();
    // ---- FFN phase 1: 16 x 128 cols per wave, K=128, A from LDS ----
    int wid = tid >> 6;
    int lane = tid & 63;
    int lr = lane & 15;
    int lk = (lane >> 4) * 8;
    int orow = (lane >> 4) * 4;
    const short* B1 = (const short*)W1T;
    int c0 = wid * 128;
    f32x4_t acc1[8] = {};
    #pragma unroll
    for (int kc = 0; kc < 4; kc++) {
        bf16x8_t af = *(const bf16x8_t*)(abt + lr * ABSTRIDE + kc * 32 + lk);
        bf16x8_t bfr[8];
        #pragma unroll
        for (int ni = 0; ni < 8; ni++)
            bfr[ni] = *(const bf16x8_t*)(B1 + (size_t)(c0 + ni * 16 + lr) * D + kc * 32 + lk);
        #pragma unroll
        for (int ni = 0; ni < 8; ni++)
            acc1[ni] = __builtin_amdgcn_mfma_f32_16x16x32_bf16(af, bfr[ni], acc1[ni], 0, 0, 0);
    }
    #pragma unroll
    for (int ni = 0; ni < 8; ni++) {
        int col = c0 + ni * 16 + lr;
        float bias = b1[col];
        #pragma unroll
        for (int j = 0; j < 4; j++) {
            float x = acc1[ni][j] + bias;
            float g = 0.5f * x * (1.f + erff(x * 0.70710678f));
            tl[(orow + j) * TSTRIDE + col] = f2bf(g);
        }
    }
    __syncthreads();
    // ---- FFN phase 2: 16 x 32 cols per wave, K=512 from LDS ----
    int c2 = wid * 32;
    const short* B2 = (const short*)W2T;
    f32x4_t acc2[2] = {};
    #pragma unroll 4
    for (int kc = 0; kc < 16; kc++) {
        bf16x8_t af, bfr[2];
        af = *(const bf16x8_t*)(tl + (size_t)lr * TSTRIDE + kc * 32 + lk);
        #pragma unroll
        for (int ni = 0; ni < 2; ni++)
            bfr[ni] = *(const bf16x8_t*)(B2 + (size_t)(c2 + ni * 16 + lr) * DFF + kc * 32 + lk);
        #pragma unroll
        for (int ni = 0; ni < 2; ni++)
            acc2[ni] = __builtin_amdgcn_mfma_f32_16x16x32_bf16(af, bfr[ni], acc2[ni], 0, 0, 0);
    }
    #pragma unroll
    for (int ni = 0; ni < 2; ni++) {
        int col = c2 + ni * 16 + lr;
        float bias = b2[col];
        #pragma unroll
        for (int j = 0; j < 4; j++) {
            size_t idx = (size_t)(r0 + orow + j) * D + col;
            float hn = h[idx] + acc2[ni][j] + bias;
            h[idx] = hn;
            hb[idx] = f2bf(hn);
        }
    }
}

// logits = hb(bf16 [M,128]) @ wt^T(bf16 [VOCAB,128]) -> f32 [M,VOCAB]
// R16 wave-private epilogue + THE FIX: explicit s_waitcnt lgkmcnt(0) with
// "memory" clobber between the predicated cross-lane LDS staging writes and
// the read-back. R16 failed because the compiler only inserts lgkm waits for
// REGISTER dependencies — a cross-lane LDS RAW (lane X reads what lane Y
// wrote) has none, so reads issued before writes completed. The asm pins
// program order on both sides (all are memory ops) and drains LDS.
// Structure: wave owns 32 full rows (acc[2][8]); staging wave-local; zero
// barriers after B-stage; nt stores 2 rows x 512B per instruction.
__global__ __launch_bounds__(256) void k_gemm_out(const unsigned short* __restrict__ A,
                                                  const unsigned short* __restrict__ Bt,
                                                  float* __restrict__ C) {
    __shared__ unsigned short bl[128 * 128];   // 32 KB B tile
    __shared__ float cl[4][8 * 132];           // 16.9 KB: per-wave 8-row stage
    int bx = blockIdx.x;             // VOCAB/128 = 250 (fastest)
    int bg = blockIdx.y;             // 16 band groups of 4 bands
    int tid = threadIdx.x;
    // stage B tile (contiguous 32 KB at Bt + bx*128*D) with row-XOR swizzle
    {
        const bf16x8_t* src = (const bf16x8_t*)((const short*)Bt + (size_t)bx * 128 * D);
        int row = tid >> 1;
        int base = (tid & 1) * 128;              // byte base within 256B row
        char* dst = (char*)bl + row * 256;
        #pragma unroll
        for (int i = 0; i < 8; i++) {
            int boff = base + i * 16;
            *(bf16x8_t*)(dst + (boff ^ ((row & 7) << 4))) = src[tid * 8 + i];
        }
    }
    __syncthreads();
    int wid = tid >> 6;
    int lane = tid & 63;
    int lr = lane & 15;
    int hi = lane >> 4;
    int lk = hi * 8;
    float* clw = cl[wid];
    const short* Ap = (const short*)A;
    #pragma unroll 1
    for (int w = 0; w < 4; w++) {
        int row0 = (bg * 4 + w) * 128 + wid * 32;   // wave owns 32 full rows
        f32x4_t acc[2][8] = {};
        #pragma unroll
        for (int kc = 0; kc < 4; kc++) {
            bf16x8_t af[2], bfr[8];
            #pragma unroll
            for (int mi = 0; mi < 2; mi++)
                af[mi] = *(const bf16x8_t*)(Ap + (size_t)(row0 + mi * 16 + lr) * D + kc * 32 + lk);
            #pragma unroll
            for (int ni = 0; ni < 8; ni++) {
                int brow = ni * 16 + lr;
                int boff = kc * 64 + hi * 16;
                bfr[ni] = *(const bf16x8_t*)((const char*)bl + brow * 256 + (boff ^ ((brow & 7) << 4)));
            }
            #pragma unroll
            for (int mi = 0; mi < 2; mi++)
                #pragma unroll
                for (int ni = 0; ni < 8; ni++)
                    acc[mi][ni] = __builtin_amdgcn_mfma_f32_16x16x32_bf16(af[mi], bfr[ni], acc[mi][ni], 0, 0, 0);
        }
        // wave-private epilogue: 4 chunks of 8 rows, no block barriers.
        #pragma unroll
        for (int c = 0; c < 4; c++) {
            int mi = c >> 1;                 // acc row-tile
            int hp = c & 1;                  // hi-pair: rows mi*16 + hp*8 .. +7
            if ((hi >> 1) == hp) {           // 32 lanes hold this chunk's data
                int rbase = (hi & 1) * 4;
                #pragma unroll
                for (int ni = 0; ni < 8; ni++)
                    #pragma unroll
                    for (int j = 0; j < 4; j++)
                        clw[(rbase + j) * 132 + ni * 16 + lr] = acc[mi][ni][j];
            }
            // Cross-lane LDS RAW: compiler tracks only register deps, so force
            // completion + program order explicitly (R16 failed without this).
            asm volatile("s_waitcnt lgkmcnt(0)" ::: "memory");
            float* Cb = C + (size_t)(row0 + mi * 16 + hp * 8) * VOCAB + bx * 128;
            #pragma unroll
            for (int k = 0; k < 4; k++) {
                int idx = k * 64 + lane;
                int rr = idx >> 5;           // 0..7 across k
                int c4 = idx & 31;
                f32x4_t v = *(const f32x4_t*)(clw + rr * 132 + c4 * 4);
                __builtin_nontemporal_store(v, (f32x4_t*)(Cb + (size_t)rr * VOCAB + c4 * 4));
            }
            // Reads of this chunk precede next chunk's writes in program order;
            // per-wave LDS ops complete in order, so clw reuse is safe. Pin it:
            asm volatile("" ::: "memory");
        }
    }
}

extern "C" void kernel_launch(void* const* d_in, const int* in_sizes, int n_in,
                              void* d_out, int out_size, void* d_ws, size_t ws_size,
                              hipStream_t stream) {
    const int*   tokens = (const int*)d_in[0];
    const float* embed  = (const float*)d_in[1];
    const float* pos    = (const float*)d_in[2];
    const float* Wq     = (const float*)d_in[3];
    const float* Wk     = (const float*)d_in[4];
    const float* Wv     = (const float*)d_in[5];
    const float* proj   = (const float*)d_in[6];
    const float* lng    = (const float*)d_in[7];
    const float* lnb    = (const float*)d_in[8];
    const float* W1     = (const float*)d_in[9];
    const float* b1     = (const float*)d_in[10];
    const float* W2     = (const float*)d_in[11];
    const float* b2     = (const float*)d_in[12];
    const float* Wout   = (const float*)d_in[13];
    float* out = (float*)d_out;
    char* ws = (char*)d_ws;

    // ws layout (MB offsets)
    float*          h    = (float*)(ws);                               // [0,4)
    unsigned short* hb   = (unsigned short*)(ws + ((size_t)4  << 20)); // [4,6)
    float*          qp   = (float*)(ws + ((size_t)6  << 20));          // [6,8)
    float*          kp   = (float*)(ws + ((size_t)8  << 20));          // [8,10)
    unsigned short* vb   = (unsigned short*)(ws + ((size_t)10 << 20)); // [10,12)
    float*          kv   = (float*)(ws + ((size_t)13 << 20));          // 64KB
    unsigned short* wt   = (unsigned short*)(ws + ((size_t)24 << 20)); // [24,32)
    unsigned short* bqkv = (unsigned short*)(ws + ((size_t)32 << 20)); // 128KB
    unsigned short* w1t  = (unsigned short*)(ws + ((size_t)33 << 20)); // 256KB
    unsigned short* w2t  = (unsigned short*)(ws + ((size_t)34 << 20)); // 256KB

    k_prep_all<<<dim3(6304), dim3(256), 0, stream>>>(tokens, embed, pos, h, hb,
                                                     Wout, wt, Wq, Wk, Wv, proj, bqkv,
                                                     W1, w1t, W2, w2t);

    for (int i = 0; i < NL; i++) {
        k_qkvp<<<dim3(M / 32), dim3(256), 0, stream>>>(hb, bqkv + (size_t)i * 256 * D, qp, kp, vb, kv);
        k_kvpart<<<dim3(P, 16, BATCH), dim3(128), 0, stream>>>(kp, vb, kv);
        k_attnffn<<<dim3(M / 16), dim3(256), 0, stream>>>(qp, kv, lng + (size_t)i * D, lnb + (size_t)i * D,
                                                          w1t + (size_t)i * DFF * D, b1 + (size_t)i * DFF,
                                                          w2t + (size_t)i * D * DFF, b2 + (size_t)i * D, h, hb);
    }

    k_gemm_out<<<dim3(VOCAB / 128, M / 128 / 4), dim3(256), 0, stream>>>(hb, wt, out);
}